// Round 1
// baseline (279.342 us; speedup 1.0000x reference)
//
#include <hip/hip_runtime.h>
#include <cstdint>
#include <cstddef>

#define E_N 500000
#define FD 128
#define TD 100
#define OD 128
#define NT 4
#define IND 228   // FD + TD
#define KP 256    // K padded to MFMA multiple

// workspace layout (bytes)
static constexpr size_t BUCKET_OFF = 0;                               // int[E_N] = 2,000,000
static constexpr size_t WBF_OFF    = 2000000;                         // bf16[NT][OD][KP] = 262,144
static constexpr size_t BIASC_OFF  = WBF_OFF + (size_t)NT * OD * KP * 2;  // float[NT][OD] = 2048
static constexpr size_t CTR_OFF    = BIASC_OFF + (size_t)NT * OD * 4;     // int[16]
static constexpr size_t WS_NEED    = CTR_OFF + 64;

typedef __attribute__((ext_vector_type(8))) short short8;
typedef __attribute__((ext_vector_type(4))) float f32x4;

__device__ __forceinline__ unsigned short f2bf(float x) {
  union { float f; unsigned u; } v; v.f = x;
  unsigned r = v.u + 0x7fff + ((v.u >> 16) & 1);   // RNE, inputs are finite
  return (unsigned short)(r >> 16);
}

// swizzled byte offset into the A tile: row r (0..63), k elem (0..255), bf16.
// XOR spreads stride-512B rows across 8 distinct 16B bank slots (G4).
__device__ __forceinline__ int a_off(int r, int k) {
  return ((r << 9) + (k << 1)) ^ ((r & 7) << 4);
}

__global__ void init_kernel(int* ctr) {
  if (threadIdx.x < 16) ctr[threadIdx.x] = 0;
}

__global__ void hist_kernel(const int* __restrict__ types, int* __restrict__ counts, int n) {
  __shared__ int lc[NT];
  if (threadIdx.x < NT) lc[threadIdx.x] = 0;
  __syncthreads();
  int i = blockIdx.x * blockDim.x + threadIdx.x;
  int stride = gridDim.x * blockDim.x;
  for (; i < n; i += stride) atomicAdd(&lc[types[i]], 1);
  __syncthreads();
  if (threadIdx.x < NT) atomicAdd(&counts[threadIdx.x], lc[threadIdx.x]);
}

// ctr[0..3]=counts, ctr[4..7]=offsets, ctr[8..11]=cursors. Also fuse bias precompute.
__global__ void scan_bias_kernel(int* __restrict__ ctr, const float* __restrict__ b,
                                 const float* __restrict__ temb, float* __restrict__ biasc) {
  if (threadIdx.x == 0) {
    int off = 0;
    for (int t = 0; t < NT; ++t) { ctr[4 + t] = off; ctr[8 + t] = off; off += ctr[t]; }
  }
  for (int i = threadIdx.x; i < NT * OD; i += blockDim.x) biasc[i] = b[i] + temb[i];
}

// W [NT][IND][OD] f32 -> Wbf [NT][OD][KP] bf16 (N-major, K zero-padded beyond 228)
__global__ void wconv_kernel(const float* __restrict__ W, unsigned short* __restrict__ Wbf) {
  int row = blockIdx.x * 4 + (threadIdx.x >> 6);   // row = t*OD + n, 0..511
  int t = row >> 7, n = row & 127;
  int k0 = (threadIdx.x & 63) << 2;
  ushort4 o;
  float v0 = (k0 + 0 < IND) ? W[((size_t)t * IND + k0 + 0) * OD + n] : 0.f;
  float v1 = (k0 + 1 < IND) ? W[((size_t)t * IND + k0 + 1) * OD + n] : 0.f;
  float v2 = (k0 + 2 < IND) ? W[((size_t)t * IND + k0 + 2) * OD + n] : 0.f;
  float v3 = (k0 + 3 < IND) ? W[((size_t)t * IND + k0 + 3) * OD + n] : 0.f;
  o.x = f2bf(v0); o.y = f2bf(v1); o.z = f2bf(v2); o.w = f2bf(v3);
  *(ushort4*)(Wbf + ((size_t)row << 8) + k0) = o;
}

// ballot-compacted bucket fill: 1 atomic per (block,type), order within type is
// atomics-nondeterministic but per-edge results are position-invariant -> output deterministic.
__global__ void fill_kernel(const int* __restrict__ types, int* __restrict__ bucket,
                            int* __restrict__ cursors, int n) {
  __shared__ int wcnt[4][NT];
  __shared__ int wbase[4][NT];
  int tid = threadIdx.x, w = tid >> 6, l = tid & 63;
  int i = blockIdx.x * 256 + tid;
  int t = (i < n) ? types[i] : -1;
  unsigned long long m[NT];
  #pragma unroll
  for (int tt = 0; tt < NT; ++tt) m[tt] = __ballot(t == tt);
  if (l == 0) {
    #pragma unroll
    for (int tt = 0; tt < NT; ++tt) wcnt[w][tt] = (int)__popcll(m[tt]);
  }
  __syncthreads();
  if (tid < NT) {
    int tt = tid, s[4], tot = 0;
    #pragma unroll
    for (int w2 = 0; w2 < 4; ++w2) { s[w2] = tot; tot += wcnt[w2][tt]; }
    int base = atomicAdd(&cursors[tt], tot);
    #pragma unroll
    for (int w2 = 0; w2 < 4; ++w2) wbase[w2][tt] = base + s[w2];
  }
  __syncthreads();
  if (t >= 0) {
    int pos = wbase[w][t] + (int)__popcll(m[t] & ((1ull << l) - 1ull));
    bucket[pos] = i;
  }
}

// Main kernel: block = 64 edges of one type x 128 out cols. K=256 (padded).
// 4 waves: wave w owns cols [w*32, w*32+32) with persistent B frags (64 VGPR).
__global__ __launch_bounds__(256) void gemm_kernel(
    const float* __restrict__ feats, const float* __restrict__ ts,
    const float* __restrict__ freqs, const unsigned short* __restrict__ Wbf,
    const float* __restrict__ biasc, const int* __restrict__ bucket,
    const int* __restrict__ ctr, float* __restrict__ out) {
  __shared__ char smraw[64 * 132 * 4];   // A tile bf16 [64][256] swizzled, reused as f32 [64][132]
  __shared__ int eidx[64];
  __shared__ float sts[64];

  const int t = blockIdx.y;
  const int cnt = ctr[t];
  const int off = ctr[4 + t];
  const int m0 = blockIdx.x * 64;
  if (m0 >= cnt) return;
  const int valid = min(64, cnt - m0);

  const int tid = threadIdx.x;
  const int wid = tid >> 6, lane = tid & 63;
  const int bl = lane & 15, bh = lane >> 4;

  // persistent B fragments, issued early so the L2 loads overlap A staging
  short8 bfrag[8][2];
  #pragma unroll
  for (int n = 0; n < 2; ++n) {
    const unsigned short* bp =
        Wbf + (((size_t)t * OD + wid * 32 + n * 16 + bl) << 8) + (bh << 3);
    #pragma unroll
    for (int k = 0; k < 8; ++k) bfrag[k][n] = *(const short8*)(bp + k * 32);
  }

  if (tid < 64) {
    int e = (tid < valid) ? bucket[off + m0 + tid] : -1;
    eidx[tid] = e;
    sts[tid] = (e >= 0) ? ts[e] : 0.f;
  }
  __syncthreads();

  {  // stage A: 4 threads per row; parts 0/1 = feats->bf16, parts 2/3 = cos time feats
    const int r = tid >> 2, part = tid & 3;
    const int e = eidx[r];
    if (part < 2) {
      const int k0 = part << 6;
      if (e >= 0) {
        const float4* src = (const float4*)(feats + (size_t)e * FD + k0);
        #pragma unroll
        for (int c = 0; c < 8; ++c) {
          float4 f0 = src[2 * c], f1 = src[2 * c + 1];
          union { uint4 u; unsigned short s[8]; } pk;
          pk.s[0] = f2bf(f0.x); pk.s[1] = f2bf(f0.y); pk.s[2] = f2bf(f0.z); pk.s[3] = f2bf(f0.w);
          pk.s[4] = f2bf(f1.x); pk.s[5] = f2bf(f1.y); pk.s[6] = f2bf(f1.z); pk.s[7] = f2bf(f1.w);
          *(uint4*)(smraw + a_off(r, k0 + c * 8)) = pk.u;
        }
      } else {
        uint4 z = make_uint4(0, 0, 0, 0);
        #pragma unroll
        for (int c = 0; c < 8; ++c) *(uint4*)(smraw + a_off(r, k0 + c * 8)) = z;
      }
    } else {
      const int d0 = (part - 2) << 6;
      const float tv = sts[r];
      const bool ok = (e >= 0);
      #pragma unroll
      for (int c = 0; c < 8; ++c) {
        union { uint4 u; unsigned short s[8]; } pk;
        #pragma unroll
        for (int j = 0; j < 8; ++j) {
          int d = d0 + c * 8 + j;
          float fr = (d < TD) ? freqs[t * TD + d] : 0.f;  // pad: cos(0)=1, W rows are 0 there
          pk.s[j] = f2bf(ok ? __cosf(tv * fr) : 0.f);
        }
        *(uint4*)(smraw + a_off(r, FD + d0 + c * 8)) = pk.u;
      }
    }
  }
  __syncthreads();

  // MFMA: acc[row-tile][n-tile], K fully resident in LDS
  f32x4 acc[4][2] = {};
  #pragma unroll
  for (int rt = 0; rt < 4; ++rt) {
    #pragma unroll
    for (int k = 0; k < 8; ++k) {
      short8 a = *(const short8*)(smraw + a_off(rt * 16 + bl, k * 32 + bh * 8));
      acc[rt][0] = __builtin_amdgcn_mfma_f32_16x16x32_bf16(a, bfrag[k][0], acc[rt][0], 0, 0, 0);
      acc[rt][1] = __builtin_amdgcn_mfma_f32_16x16x32_bf16(a, bfrag[k][1], acc[rt][1], 0, 0, 0);
    }
  }
  __syncthreads();

  // epilogue via LDS for coalesced float4 row writes; C/D map: col=lane&15, row=(lane>>4)*4+j
  float* smo = (float*)smraw;
  #pragma unroll
  for (int rt = 0; rt < 4; ++rt)
    #pragma unroll
    for (int n = 0; n < 2; ++n)
      #pragma unroll
      for (int j = 0; j < 4; ++j)
        smo[(rt * 16 + bh * 4 + j) * 132 + wid * 32 + n * 16 + bl] = acc[rt][n][j];
  __syncthreads();

  const int orow = tid >> 2;
  if (orow < valid) {
    const int e = eidx[orow];
    const int c0 = (tid & 3) << 5;
    const float4* bv = (const float4*)(biasc + t * OD + c0);
    float4* dst = (float4*)(out + (size_t)e * OD + c0);
    #pragma unroll
    for (int c = 0; c < 8; ++c) {
      float4 v = *(const float4*)(smo + orow * 132 + c0 + c * 4);
      float4 bb = bv[c];
      v.x += bb.x; v.y += bb.y; v.z += bb.z; v.w += bb.w;
      dst[c] = v;
    }
  }
}

// correctness fallback if ws is too small for bucketing (fp32 vector path)
__global__ void naive_kernel(const float* __restrict__ feats, const float* __restrict__ ts,
                             const int* __restrict__ types, const float* __restrict__ W,
                             const float* __restrict__ b, const float* __restrict__ temb,
                             const float* __restrict__ freqs, float* __restrict__ out) {
  __shared__ float comb[IND];
  int e = blockIdx.x;
  int t = types[e];
  int tid = threadIdx.x;  // 128 threads
  comb[tid] = feats[(size_t)e * FD + tid];
  if (tid < TD) comb[FD + tid] = __cosf(ts[e] * freqs[t * TD + tid]);
  __syncthreads();
  float acc = b[t * OD + tid] + temb[t * OD + tid];
  for (int k = 0; k < IND; ++k) acc += comb[k] * W[((size_t)t * IND + k) * OD + tid];
  out[(size_t)e * OD + tid] = acc;
}

extern "C" void kernel_launch(void* const* d_in, const int* in_sizes, int n_in,
                              void* d_out, int out_size, void* d_ws, size_t ws_size,
                              hipStream_t stream) {
  const float* feats = (const float*)d_in[0];
  const float* ts    = (const float*)d_in[1];
  const int*   types = (const int*)d_in[2];
  const float* W     = (const float*)d_in[3];
  const float* bb    = (const float*)d_in[4];
  const float* temb  = (const float*)d_in[5];
  const float* freqs = (const float*)d_in[6];
  float* out = (float*)d_out;

  if (ws_size < WS_NEED) {
    naive_kernel<<<E_N, 128, 0, stream>>>(feats, ts, types, W, bb, temb, freqs, out);
    return;
  }

  char* ws = (char*)d_ws;
  int* bucket = (int*)(ws + BUCKET_OFF);
  unsigned short* Wbf = (unsigned short*)(ws + WBF_OFF);
  float* biasc = (float*)(ws + BIASC_OFF);
  int* ctr = (int*)(ws + CTR_OFF);

  init_kernel<<<1, 16, 0, stream>>>(ctr);
  hist_kernel<<<1024, 256, 0, stream>>>(types, ctr, E_N);
  scan_bias_kernel<<<1, 256, 0, stream>>>(ctr, bb, temb, biasc);
  wconv_kernel<<<(NT * OD) / 4, 256, 0, stream>>>(W, Wbf);
  fill_kernel<<<(E_N + 255) / 256, 256, 0, stream>>>(types, bucket, ctr + 8, E_N);
  dim3 g((E_N + 63) / 64, NT);
  gemm_kernel<<<g, 256, 0, stream>>>(feats, ts, freqs, Wbf, biasc, bucket, ctr, out);
}

// Round 4
// 223.361 us; speedup vs baseline: 1.2506x; 1.2506x over previous
//
#include <hip/hip_runtime.h>
#include <cstdint>
#include <cstddef>

#define E_N 500000
#define FD 128
#define TD 100
#define OD 128
#define NT 4
#define IND 228   // FD + TD
#define KP 256    // K padded to MFMA multiple
#define GX 256    // blocks per type for gemm

// workspace layout (bytes)
static constexpr size_t BUCKET_OFF = 0;                                   // int[E_N] = 2,000,000
static constexpr size_t WBF_OFF    = 2000000;                             // bf16[NT][OD][KP] = 262,144
static constexpr size_t BIASC_OFF  = WBF_OFF + (size_t)NT * OD * KP * 2;  // float[NT][OD] = 2048
static constexpr size_t CTR_OFF    = BIASC_OFF + (size_t)NT * OD * 4;     // int[16]
static constexpr size_t WS_NEED    = CTR_OFF + 64;

typedef __attribute__((ext_vector_type(8))) short short8;
typedef __attribute__((ext_vector_type(4))) float f32x4;

__device__ __forceinline__ unsigned short f2bf(float x) {
  union { float f; unsigned u; } v; v.f = x;
  unsigned r = v.u + 0x7fff + ((v.u >> 16) & 1);   // RNE, inputs are finite
  return (unsigned short)(r >> 16);
}

// swizzled byte offset into the A tile: row r (0..63), k elem (0..255), bf16.
// XOR spreads stride-512B rows across 8 distinct 16B bank slots (G4).
__device__ __forceinline__ int a_off(int r, int k) {
  return ((r << 9) + (k << 1)) ^ ((r & 7) << 4);
}

__global__ void init_kernel(int* ctr) {
  if (threadIdx.x < 16) ctr[threadIdx.x] = 0;
}

__global__ void hist_kernel(const int* __restrict__ types, int* __restrict__ counts, int n) {
  __shared__ int lc[NT];
  if (threadIdx.x < NT) lc[threadIdx.x] = 0;
  __syncthreads();
  int i = blockIdx.x * blockDim.x + threadIdx.x;
  int stride = gridDim.x * blockDim.x;
  for (; i < n; i += stride) atomicAdd(&lc[types[i]], 1);
  __syncthreads();
  if (threadIdx.x < NT) atomicAdd(&counts[threadIdx.x], lc[threadIdx.x]);
}

// ctr[0..3]=counts, ctr[4..7]=offsets, ctr[8..11]=cursors. Also fuse bias precompute.
__global__ void scan_bias_kernel(int* __restrict__ ctr, const float* __restrict__ b,
                                 const float* __restrict__ temb, float* __restrict__ biasc) {
  if (threadIdx.x == 0) {
    int off = 0;
    for (int t = 0; t < NT; ++t) { ctr[4 + t] = off; ctr[8 + t] = off; off += ctr[t]; }
  }
  for (int i = threadIdx.x; i < NT * OD; i += blockDim.x) biasc[i] = b[i] + temb[i];
}

// W [NT][IND][OD] f32 -> Wbf [NT][OD][KP] bf16 (N-major, K zero-padded beyond 228)
__global__ void wconv_kernel(const float* __restrict__ W, unsigned short* __restrict__ Wbf) {
  int row = blockIdx.x * 4 + (threadIdx.x >> 6);   // row = t*OD + n, 0..511
  int t = row >> 7, n = row & 127;
  int k0 = (threadIdx.x & 63) << 2;
  ushort4 o;
  float v0 = (k0 + 0 < IND) ? W[((size_t)t * IND + k0 + 0) * OD + n] : 0.f;
  float v1 = (k0 + 1 < IND) ? W[((size_t)t * IND + k0 + 1) * OD + n] : 0.f;
  float v2 = (k0 + 2 < IND) ? W[((size_t)t * IND + k0 + 2) * OD + n] : 0.f;
  float v3 = (k0 + 3 < IND) ? W[((size_t)t * IND + k0 + 3) * OD + n] : 0.f;
  o.x = f2bf(v0); o.y = f2bf(v1); o.z = f2bf(v2); o.w = f2bf(v3);
  *(ushort4*)(Wbf + ((size_t)row << 8) + k0) = o;
}

// ballot-compacted bucket fill: 1 atomic per (block,type); order within type is
// atomics-nondeterministic but per-edge results are position-invariant -> deterministic output.
__global__ void fill_kernel(const int* __restrict__ types, int* __restrict__ bucket,
                            int* __restrict__ cursors, int n) {
  __shared__ int wcnt[4][NT];
  __shared__ int wbase[4][NT];
  int tid = threadIdx.x, w = tid >> 6, l = tid & 63;
  int i = blockIdx.x * 256 + tid;
  int t = (i < n) ? types[i] : -1;
  unsigned long long m[NT];
  #pragma unroll
  for (int tt = 0; tt < NT; ++tt) m[tt] = __ballot(t == tt);
  if (l == 0) {
    #pragma unroll
    for (int tt = 0; tt < NT; ++tt) wcnt[w][tt] = (int)__popcll(m[tt]);
  }
  __syncthreads();
  if (tid < NT) {
    int tt = tid, s[4], tot = 0;
    #pragma unroll
    for (int w2 = 0; w2 < 4; ++w2) { s[w2] = tot; tot += wcnt[w2][tt]; }
    int base = atomicAdd(&cursors[tt], tot);
    #pragma unroll
    for (int w2 = 0; w2 < 4; ++w2) wbase[w2][tt] = base + s[w2];
  }
  __syncthreads();
  if (t >= 0) {
    int pos = wbase[w][t] + (int)__popcll(m[t] & ((1ull << l) - 1ull));
    bucket[pos] = i;
  }
}

// Main kernel: block owns a contiguous chunk of 64-edge tiles of one type.
// All per-edge indices live in REGISTERS (loaded directly from bucket/ts; the
// x4 redundancy across parts is L1/L2 hits) -- no LDS index buffers, no race
// surface. Register prefetch of next tile's feats rides under MFMA+epilogue.
__global__ __launch_bounds__(256) void gemm_kernel(
    const float* __restrict__ feats, const float* __restrict__ ts,
    const float* __restrict__ freqs, const unsigned short* __restrict__ Wbf,
    const float* __restrict__ biasc, const int* __restrict__ bucket,
    const int* __restrict__ ctr, float* __restrict__ out) {
  __shared__ __align__(16) char smraw[64 * 132 * 4];   // A tile bf16 [64][256] swizzled / epilogue f32 [64][132]
  __shared__ __align__(16) float sfreq[128];

  const int t = blockIdx.y;
  const int cnt = ctr[t];
  const int off = ctr[4 + t];
  const int ntiles = (cnt + 63) >> 6;
  const int chunk = (ntiles + GX - 1) / GX;
  const int t0 = blockIdx.x * chunk;
  const int t1 = min(t0 + chunk, ntiles);
  if (t0 >= t1) return;

  const int tid = threadIdx.x;
  const int wid = tid >> 6, lane = tid & 63;
  const int bl = lane & 15, bh = lane >> 4;
  const int r = tid >> 2, part = tid & 3;   // 4 threads per A-row; part = 32-elem k-window

  // persistent B fragments (L2-resident Wbf)
  short8 bfrag[8][2];
  #pragma unroll
  for (int n = 0; n < 2; ++n) {
    const unsigned short* bp =
        Wbf + (((size_t)t * OD + wid * 32 + n * 16 + bl) << 8) + (bh << 3);
    #pragma unroll
    for (int k = 0; k < 8; ++k) bfrag[k][n] = *(const short8*)(bp + k * 32);
  }

  if (tid < 128) sfreq[tid] = (tid < TD) ? freqs[t * TD + tid] : 0.f;

  // register prefetch of tile t0 (this thread's row r)
  int e_cur = -1; float tv_cur = 0.f;
  float4 pf[8];
  {
    const int v0 = min(64, cnt - t0 * 64);
    if (r < v0) {
      e_cur = bucket[off + t0 * 64 + r];
      tv_cur = ts[e_cur];
      const float4* src = (const float4*)(feats + (size_t)e_cur * FD + part * 32);
      #pragma unroll
      for (int c = 0; c < 8; ++c) pf[c] = src[c];
    }
  }
  int e_nxt = -1; float tv_nxt = 0.f;

  for (int tt = t0; tt < t1; ++tt) {
    __syncthreads();   // sync0: sfreq ready (iter 0) / prev epilogue smo-reads done

    // ---- stage tile tt: feats window + cos time window, both zeroed if row invalid ----
    {
      union { unsigned short s[32]; uint4 v4[4]; } pk;
      union { unsigned short s[32]; uint4 v4[4]; } tk;
      if (e_cur >= 0) {
        #pragma unroll
        for (int c = 0; c < 8; ++c) {
          pk.s[4 * c + 0] = f2bf(pf[c].x); pk.s[4 * c + 1] = f2bf(pf[c].y);
          pk.s[4 * c + 2] = f2bf(pf[c].z); pk.s[4 * c + 3] = f2bf(pf[c].w);
        }
        #pragma unroll
        for (int m = 0; m < 8; ++m) {
          float4 fq = *(const float4*)&sfreq[part * 32 + 4 * m];
          tk.s[4 * m + 0] = f2bf(__cosf(tv_cur * fq.x));
          tk.s[4 * m + 1] = f2bf(__cosf(tv_cur * fq.y));
          tk.s[4 * m + 2] = f2bf(__cosf(tv_cur * fq.z));
          tk.s[4 * m + 3] = f2bf(__cosf(tv_cur * fq.w));
        }
      } else {
        uint4 z = make_uint4(0, 0, 0, 0);
        #pragma unroll
        for (int j = 0; j < 4; ++j) { pk.v4[j] = z; tk.v4[j] = z; }
      }
      #pragma unroll
      for (int j = 0; j < 4; ++j)
        *(uint4*)(smraw + a_off(r, part * 32 + 8 * j)) = pk.v4[j];
      #pragma unroll
      for (int j = 0; j < 4; ++j)
        *(uint4*)(smraw + a_off(r, FD + part * 32 + 8 * j)) = tk.v4[j];
    }
    __syncthreads();   // sync1: A ready

    // ---- register prefetch of tile tt+1 (vmcnt-tracked; hides under MFMA+epilogue) ----
    if (tt + 1 < t1) {
      const int vn = min(64, cnt - (tt + 1) * 64);
      e_nxt = -1; tv_nxt = 0.f;
      if (r < vn) {
        e_nxt = bucket[off + (tt + 1) * 64 + r];
        tv_nxt = ts[e_nxt];
        const float4* src = (const float4*)(feats + (size_t)e_nxt * FD + part * 32);
        #pragma unroll
        for (int c = 0; c < 8; ++c) pf[c] = src[c];
      }
    }

    // ---- MFMA ----
    f32x4 acc[4][2] = {};
    __builtin_amdgcn_s_setprio(1);
    #pragma unroll
    for (int rt = 0; rt < 4; ++rt) {
      #pragma unroll
      for (int k = 0; k < 8; ++k) {
        short8 a = *(const short8*)(smraw + a_off(rt * 16 + bl, k * 32 + bh * 8));
        acc[rt][0] = __builtin_amdgcn_mfma_f32_16x16x32_bf16(a, bfrag[k][0], acc[rt][0], 0, 0, 0);
        acc[rt][1] = __builtin_amdgcn_mfma_f32_16x16x32_bf16(a, bfrag[k][1], acc[rt][1], 0, 0, 0);
      }
    }
    __builtin_amdgcn_s_setprio(0);
    __syncthreads();   // sync2: all A reads done; region reusable

    // ---- epilogue: smo [64][132] f32, then coalesced row writes (r1-proven) ----
    float* smo = (float*)smraw;
    #pragma unroll
    for (int rt = 0; rt < 4; ++rt)
      #pragma unroll
      for (int n = 0; n < 2; ++n)
        #pragma unroll
        for (int j = 0; j < 4; ++j)
          smo[(rt * 16 + bh * 4 + j) * 132 + wid * 32 + n * 16 + bl] = acc[rt][n][j];
    __syncthreads();   // sync3: smo ready

    if (e_cur >= 0) {
      const int c0 = part << 5;
      const float4* bv = (const float4*)(biasc + t * OD + c0);
      float4* dst = (float4*)(out + (size_t)e_cur * OD + c0);
      const float* smrow = smo + r * 132 + c0;
      #pragma unroll
      for (int c = 0; c < 8; ++c) {
        float4 v = *(const float4*)(smrow + 4 * c);
        float4 bb = bv[c];
        v.x += bb.x; v.y += bb.y; v.z += bb.z; v.w += bb.w;
        dst[c] = v;
      }
    }
    e_cur = e_nxt; tv_cur = tv_nxt;
  }
}

// correctness fallback if ws is too small for bucketing (fp32 vector path)
__global__ void naive_kernel(const float* __restrict__ feats, const float* __restrict__ ts,
                             const int* __restrict__ types, const float* __restrict__ W,
                             const float* __restrict__ b, const float* __restrict__ temb,
                             const float* __restrict__ freqs, float* __restrict__ out) {
  __shared__ float comb[IND];
  int e = blockIdx.x;
  int t = types[e];
  int tid = threadIdx.x;  // 128 threads
  comb[tid] = feats[(size_t)e * FD + tid];
  if (tid < TD) comb[FD + tid] = __cosf(ts[e] * freqs[t * TD + tid]);
  __syncthreads();
  float acc = b[t * OD + tid] + temb[t * OD + tid];
  for (int k = 0; k < IND; ++k) acc += comb[k] * W[((size_t)t * IND + k) * OD + tid];
  out[(size_t)e * OD + tid] = acc;
}

extern "C" void kernel_launch(void* const* d_in, const int* in_sizes, int n_in,
                              void* d_out, int out_size, void* d_ws, size_t ws_size,
                              hipStream_t stream) {
  const float* feats = (const float*)d_in[0];
  const float* ts    = (const float*)d_in[1];
  const int*   types = (const int*)d_in[2];
  const float* W     = (const float*)d_in[3];
  const float* bb    = (const float*)d_in[4];
  const float* temb  = (const float*)d_in[5];
  const float* freqs = (const float*)d_in[6];
  float* out = (float*)d_out;

  if (ws_size < WS_NEED) {
    naive_kernel<<<E_N, 128, 0, stream>>>(feats, ts, types, W, bb, temb, freqs, out);
    return;
  }

  char* ws = (char*)d_ws;
  int* bucket = (int*)(ws + BUCKET_OFF);
  unsigned short* Wbf = (unsigned short*)(ws + WBF_OFF);
  float* biasc = (float*)(ws + BIASC_OFF);
  int* ctr = (int*)(ws + CTR_OFF);

  init_kernel<<<1, 16, 0, stream>>>(ctr);
  hist_kernel<<<1024, 256, 0, stream>>>(types, ctr, E_N);
  scan_bias_kernel<<<1, 256, 0, stream>>>(ctr, bb, temb, biasc);
  wconv_kernel<<<(NT * OD) / 4, 256, 0, stream>>>(W, Wbf);
  fill_kernel<<<(E_N + 255) / 256, 256, 0, stream>>>(types, bucket, ctr + 8, E_N);
  dim3 g(GX, NT);
  gemm_kernel<<<g, 256, 0, stream>>>(feats, ts, freqs, Wbf, biasc, bucket, ctr, out);
}